// Round 4
// baseline (619.039 us; speedup 1.0000x reference)
//
#include <hip/hip_runtime.h>
#include <cstdio>

// ---------------------------------------------------------------------------
// BiLSTM  B=64, T=512, D=256, H=256
//   P0: x -> bf16; Wih -> bf16 with gate-permuted rows (n -> (n&255)*4+(n>>8));
//       permuted bias vectors; Whh -> int8 packed into mfma_i32_16x16x64_i8
//       A-fragment order wmf[d][Mt][Kt][lane][4dw]
//   P1: MFMA bf16 GEMM (contiguous epilogue) -> xproj[d][b*512+t][j*4+gate]
//   P2: recurrence: 128 WGs (64 batch x 2 dir) x 256 thr, 4 waves (R7).
//       R5 (8 waves, half-lanes active) spent ~1900 cyc/step: the 16-col
//       B replication wasted half of every wave's tail issue, and 32
//       ds_read_b128/step clogged the shared LDS pipe. R7: wave w owns 16
//       M-tiles; lane l extracts tile (l&15) at row-group (l>>4) -> unit
//       j=(w*16+(l&15))*4+(l>>4): 256 threads == 256 units, zero masked
//       lanes, 16 ds_reads/step, tail issued once per SIMD. Weights: 256
//       dwords/thread pinned in AGPRs ("+a" ties; mfma reads A from AGPR).
//       mfma issue (64/SIMD/step ~ 320 cyc) now dominates the step.
// ---------------------------------------------------------------------------

typedef unsigned short ushort_t;
typedef __attribute__((ext_vector_type(8))) short short8;
typedef __attribute__((ext_vector_type(4))) float f32x4;
typedef __attribute__((ext_vector_type(4))) int i32x4;

__device__ __forceinline__ ushort_t f2bf(float f) {
    union { float f; unsigned u; } v; v.f = f;
    unsigned r = v.u + 0x7fffu + ((v.u >> 16) & 1u);
    return (ushort_t)(r >> 16);
}
__device__ __forceinline__ float bf2f(ushort_t h) {
    union { unsigned u; float f; } v; v.u = ((unsigned)h) << 16;
    return v.f;
}

__device__ __forceinline__ float fexp2(float x) {
#if __has_builtin(__builtin_amdgcn_exp2f)
    return __builtin_amdgcn_exp2f(x);
#else
    return exp2f(x);
#endif
}
__device__ __forceinline__ float frcp(float x) {
#if __has_builtin(__builtin_amdgcn_rcpf)
    return __builtin_amdgcn_rcpf(x);
#else
    return 1.0f / x;
#endif
}
__device__ __forceinline__ float fsig(float x) {
    return frcp(1.0f + fexp2(-1.44269504089f * x));
}
__device__ __forceinline__ float ftanh(float x) {
    float e = fexp2(2.88539008178f * x);
    return 1.0f - 2.0f * frcp(e + 1.0f);
}

// LDS-only barrier: drain lgkm (LDS ops) but NOT vmcnt.
__device__ __forceinline__ void lds_barrier() {
    asm volatile("s_waitcnt lgkmcnt(0)\n\ts_barrier" ::: "memory");
}

// ---------------------------------------------------------------------------
// P0a: fp32 -> bf16 (n multiple of 4)
__global__ __launch_bounds__(256) void k_f2bf(const float* __restrict__ in,
                                              ushort_t* __restrict__ out, int n) {
    int i = (blockIdx.x * 256 + threadIdx.x) * 4;
    if (i + 3 < n) {
        float4 v = *(const float4*)&in[i];
        ushort4 o;
        o.x = f2bf(v.x); o.y = f2bf(v.y); o.z = f2bf(v.z); o.w = f2bf(v.w);
        *(ushort4*)&out[i] = o;
    }
}

// P0b: Wih fp32 -> bf16 with gate-permuted ROW order:
//   dst[d][(n&255)*4 + (n>>8)][k] = src_d[n][k]
__global__ __launch_bounds__(256) void k_wih(const float* __restrict__ wihf,
                                             const float* __restrict__ wihb,
                                             ushort_t* __restrict__ dst) {
    int d = blockIdx.y;
    int n = blockIdx.x * 4 + (threadIdx.x >> 6);   // 0..1023
    int l = threadIdx.x & 63;
    const float* src = (d ? wihb : wihf) + (size_t)n * 256;
    float4 v = *(const float4*)&src[l * 4];
    int np = (n & 255) * 4 + (n >> 8);
    ushort4 o;
    o.x = f2bf(v.x); o.y = f2bf(v.y); o.z = f2bf(v.z); o.w = f2bf(v.w);
    *(ushort4*)&dst[((size_t)d * 1024 + np) * 256 + l * 4] = o;
}

// P0c: permuted bias vectors bv[d][(n&255)*4 + (n>>8)] = bih_d[n] + bhh_d[n]
__global__ __launch_bounds__(256) void k_bias(const float* __restrict__ bihf,
                                              const float* __restrict__ bhhf,
                                              const float* __restrict__ bihb,
                                              const float* __restrict__ bhhb,
                                              float* __restrict__ bv) {
    int i = blockIdx.x * 256 + threadIdx.x;   // 0..2047
    int d = i >> 10, n = i & 1023;
    float s = d ? (bihb[n] + bhhb[n]) : (bihf[n] + bhhf[n]);
    bv[d * 1024 + (n & 255) * 4 + (n >> 8)] = s;
}

// P0d: quantize Whh rows to int8, packed into mfma_i32_16x16x64_i8
// A-fragment order. Fragment (Mt,Kt): lane l holds row Mt*16+(l&15),
// k = Kt*64 + (l>>4)*16 + {0..15} (4 dwords, byte0 = lowest k).
// Thread here computes the packed dword for (row_p, kc=k/4):
//   Mt = row_p>>4, rl = row_p&15, Kt = kc>>4, lg = (kc>>2)&3, dw = kc&3
//   wmf[d*65536 + ((Mt*4+Kt)*64 + lg*16 + rl)*4 + dw] = packed
__global__ __launch_bounds__(256) void k_quant(const float* __restrict__ whhf,
                                               const float* __restrict__ whhb,
                                               int* __restrict__ wmf,
                                               float* __restrict__ fscale4) {
    int rowg = blockIdx.x * 4 + (threadIdx.x >> 6);   // 0..2047
    int l = threadIdx.x & 63;                          // = kc
    int d = rowg >> 10;
    int row = rowg & 1023;
    const float* W = (d ? whhb : whhf) + (size_t)row * 256;
    float4 v = *(const float4*)&W[l * 4];
    float m = fmaxf(fmaxf(fabsf(v.x), fabsf(v.y)), fmaxf(fabsf(v.z), fabsf(v.w)));
    #pragma unroll
    for (int off = 32; off > 0; off >>= 1) m = fmaxf(m, __shfl_xor(m, off));
    float inv = (m > 0.0f) ? (127.0f / m) : 0.0f;
    int q0 = __float2int_rn(v.x * inv);
    int q1 = __float2int_rn(v.y * inv);
    int q2 = __float2int_rn(v.z * inv);
    int q3 = __float2int_rn(v.w * inv);
    q0 = min(127, max(-127, q0)); q1 = min(127, max(-127, q1));
    q2 = min(127, max(-127, q2)); q3 = min(127, max(-127, q3));
    int packed = (q0 & 255) | ((q1 & 255) << 8) | ((q2 & 255) << 16) | ((q3 & 255) << 24);
    int j = row & 255, gate = row >> 8;
    int row_p = j * 4 + gate;
    int Mt = row_p >> 4, rl = row_p & 15;
    int Kt = l >> 4, lg = (l >> 2) & 3, dw = l & 3;
    wmf[d * 65536 + ((Mt * 4 + Kt) * 64 + lg * 16 + rl) * 4 + dw] = packed;
    if (l == 0) fscale4[d * 1024 + row_p] = m / (127.0f * 127.0f);
}

// ---------------------------------------------------------------------------
// P1: bf16 GEMM (contiguous epilogue; B rows pre-permuted).
#define LDSOFF(r, kc) ((r) * 32 + ((((kc) + ((r) >> 1)) & 3) * 8))

__global__ __launch_bounds__(256) void k_gemm(const ushort_t* __restrict__ A,
                                              const ushort_t* __restrict__ Bw,
                                              const float* __restrict__ biasv,
                                              ushort_t* __restrict__ Xp) {
    const int dir = blockIdx.z;
    const ushort_t* Bmat = Bw + dir * 262144;
    const float* bv = biasv + dir * 1024;
    ushort_t* C = Xp + (size_t)dir * 33554432;
    const int tn = blockIdx.x;   // 0..7
    const int tm = blockIdx.y;   // 0..255
    const int tid = threadIdx.x;
    const int w = tid >> 6, l = tid & 63;
    const int wm = w & 1, wn = w >> 1;

    __shared__ ushort_t As[128 * 32];
    __shared__ ushort_t Bs[128 * 32];

    f32x4 acc[4][4];
    #pragma unroll
    for (int i = 0; i < 4; i++)
        #pragma unroll
        for (int jj = 0; jj < 4; jj++) acc[i][jj] = (f32x4){0.f, 0.f, 0.f, 0.f};

    const int r0 = tid >> 2, c0 = tid & 3;
    const int r1 = (tid + 256) >> 2, c1 = tid & 3;

    for (int kb = 0; kb < 8; kb++) {
        __syncthreads();
        {
            short8 a0 = *(const short8*)&A[((size_t)(tm * 128 + r0)) * 256 + kb * 32 + c0 * 8];
            short8 a1 = *(const short8*)&A[((size_t)(tm * 128 + r1)) * 256 + kb * 32 + c1 * 8];
            short8 b0 = *(const short8*)&Bmat[((size_t)(tn * 128 + r0)) * 256 + kb * 32 + c0 * 8];
            short8 b1 = *(const short8*)&Bmat[((size_t)(tn * 128 + r1)) * 256 + kb * 32 + c1 * 8];
            *(short8*)&As[LDSOFF(r0, c0)] = a0;
            *(short8*)&As[LDSOFF(r1, c1)] = a1;
            *(short8*)&Bs[LDSOFF(r0, c0)] = b0;
            *(short8*)&Bs[LDSOFF(r1, c1)] = b1;
        }
        __syncthreads();
        short8 af[4], bfr[4];
        const int q = l >> 4;
        #pragma unroll
        for (int mt = 0; mt < 4; mt++) {
            int rr = wm * 64 + mt * 16 + (l & 15);
            af[mt] = *(const short8*)&As[LDSOFF(rr, q)];
        }
        #pragma unroll
        for (int nt = 0; nt < 4; nt++) {
            int rr = wn * 64 + nt * 16 + (l & 15);
            bfr[nt] = *(const short8*)&Bs[LDSOFF(rr, q)];
        }
        #pragma unroll
        for (int mt = 0; mt < 4; mt++)
            #pragma unroll
            for (int nt = 0; nt < 4; nt++)
                acc[mt][nt] = __builtin_amdgcn_mfma_f32_16x16x32_bf16(
                    af[mt], bfr[nt], acc[mt][nt], 0, 0, 0);
    }
    #pragma unroll
    for (int nt = 0; nt < 4; nt++) {
        int n = tn * 128 + wn * 64 + nt * 16 + (l & 15);
        float bn = bv[n];
        #pragma unroll
        for (int mt = 0; mt < 4; mt++) {
            #pragma unroll
            for (int rr = 0; rr < 4; rr++) {
                int m = tm * 128 + wm * 64 + mt * 16 + (l >> 4) * 4 + rr;
                C[(size_t)m * 1024 + n] = f2bf(acc[mt][nt][rr] + bn);
            }
        }
    }
}

// ---------------------------------------------------------------------------
// P2: recurrence. grid (64 batch, 2 dir) x 256 threads (4 waves).
// Wave w owns M-tiles w*16..w*16+15 (units w*64..w*64+63).
// Lane l extracts tile (l&15) at row-group (l>>4):
//   unit j = (w*16 + (l&15))*4 + (l>>4); acc regs 0..3 = gates i,f,g,o of j.
// All 256 threads map bijectively onto the 256 units: no masked lanes.
__device__ __forceinline__ int time_idx(int s, int len, int d) {
    int sc = (s < len - 1) ? s : (len - 1);
    return (d == 0) ? sc : (len - 1 - sc);
}

__global__ __launch_bounds__(256, 1) void k_rec(const ushort_t* __restrict__ xproj,
                                                const int* __restrict__ wmf,
                                                const float* __restrict__ fscale4,
                                                const int* __restrict__ lens,
                                                float* __restrict__ out) {
    const int b = blockIdx.x, d = blockIdx.y;
    const int tid = threadIdx.x;
    const int w = tid >> 6, l = tid & 63;
    int len = lens[b];
    if (len < 1) len = 1;
    if (len > 512) len = 512;
    const ushort_t* xp = xproj + ((size_t)d * 64 + b) * 524288;  // 512*1024

    const int rg = l >> 4;                   // 0..3 (row-group / k-slice)
    const int j = (w * 16 + (l & 15)) * 4 + rg;   // unit 0..255, bijective

    // 64 A-fragments (256 dwords) pinned in AGPRs ("+a" ties). mfma reads
    // A directly from AGPR on gfx950; arch-VGPR file stays free for the
    // VALU extract/tail. 1 wave/SIMD (launch_bounds 256,1): total budget
    // 512 regs/thread, need ~256 AGPR + ~150 VGPR.
    i32x4 wf[16][4];
    const int* wb = wmf + d * 65536;
    #pragma unroll
    for (int til = 0; til < 16; til++)
        #pragma unroll
        for (int kt = 0; kt < 4; kt++) {
            wf[til][kt] = *(const i32x4*)&wb[(((w * 16 + til) * 4 + kt) * 64 + l) * 4];
            asm volatile("" : "+a"(wf[til][kt]));
        }

    float4 fr = *(const float4*)&fscale4[d * 1024 + 4 * j];   // loop-invariant

    __shared__ char h8[2][256] __attribute__((aligned(16)));
    if (tid < 64) ((int*)h8)[tid] = 0;   // zero h8[0]

    // zero-fill this direction's half for t in [len, 512)
    {
        float4 z = {0.f, 0.f, 0.f, 0.f};
        int total4 = (512 - len) * 64;
        for (int i = tid; i < total4; i += 256) {
            int t = len + (i >> 6);
            int c4 = i & 63;
            *(float4*)&out[((size_t)b * 512 + t) * 512 + d * 256 + c4 * 4] = z;
        }
    }
    __syncthreads();

    float c_state = 0.0f;
    // 3-deep x prefetch ring; 8B per lane (the 4 gate pre-activations of j).
    uint2 xv0 = *(const uint2*)&xp[(size_t)time_idx(0, len, d) * 1024 + 4 * j];
    uint2 xv1 = *(const uint2*)&xp[(size_t)time_idx(1, len, d) * 1024 + 4 * j];
    uint2 xv2 = *(const uint2*)&xp[(size_t)time_idx(2, len, d) * 1024 + 4 * j];
    const i32x4 z4 = {0, 0, 0, 0};

    for (int s = 0; s < len; s++) {
        // B-operand: h replicated into all 16 cols; lane needs k-slice
        // kt*64 + rg*16 .. +15 -> 4 wave-uniform-ish ds_read_b128 (16/WG).
        const char* hb = h8[s & 1];
        i32x4 h0 = *(const i32x4*)(hb + rg * 16);
        i32x4 h1 = *(const i32x4*)(hb + 64 + rg * 16);
        i32x4 h2 = *(const i32x4*)(hb + 128 + rg * 16);
        i32x4 h3 = *(const i32x4*)(hb + 192 + rg * 16);

        uint2 xc = xv0;
        xv0 = xv1;
        xv1 = xv2;
        xv2 = *(const uint2*)&xp[(size_t)time_idx(s + 3, len, d) * 1024 + 4 * j];

        // kt-outer: the first 16 mfma depend only on h0 (fine lgkm waits).
        i32x4 acc[16];
        #pragma unroll
        for (int til = 0; til < 16; til++)
            acc[til] = __builtin_amdgcn_mfma_i32_16x16x64_i8(wf[til][0], h0, z4, 0, 0, 0);
        #pragma unroll
        for (int til = 0; til < 16; til++)
            acc[til] = __builtin_amdgcn_mfma_i32_16x16x64_i8(wf[til][1], h1, acc[til], 0, 0, 0);
        #pragma unroll
        for (int til = 0; til < 16; til++)
            acc[til] = __builtin_amdgcn_mfma_i32_16x16x64_i8(wf[til][2], h2, acc[til], 0, 0, 0);
        #pragma unroll
        for (int til = 0; til < 16; til++)
            acc[til] = __builtin_amdgcn_mfma_i32_16x16x64_i8(wf[til][3], h3, acc[til], 0, 0, 0);

        // 4-level select tree on til = l&15: u = acc[l&15].
        i32x4 a0 = (l & 1) ? acc[1] : acc[0];
        i32x4 a1 = (l & 1) ? acc[3] : acc[2];
        i32x4 a2 = (l & 1) ? acc[5] : acc[4];
        i32x4 a3 = (l & 1) ? acc[7] : acc[6];
        i32x4 a4 = (l & 1) ? acc[9] : acc[8];
        i32x4 a5 = (l & 1) ? acc[11] : acc[10];
        i32x4 a6 = (l & 1) ? acc[13] : acc[12];
        i32x4 a7 = (l & 1) ? acc[15] : acc[14];
        i32x4 b0 = (l & 2) ? a1 : a0;
        i32x4 b1 = (l & 2) ? a3 : a2;
        i32x4 b2 = (l & 2) ? a5 : a4;
        i32x4 b3 = (l & 2) ? a7 : a6;
        i32x4 c0 = (l & 4) ? b1 : b0;
        i32x4 c1 = (l & 4) ? b3 : b2;
        i32x4 u  = (l & 8) ? c1 : c0;

        // Tail: all 64 lanes useful. regs 0..3 = gates i,f,g,o of unit j.
        float pi = bf2f((ushort_t)(xc.x & 0xffffu)) + fr.x * (float)u.x;
        float pf = bf2f((ushort_t)(xc.x >> 16))     + fr.y * (float)u.y;
        float pg = bf2f((ushort_t)(xc.y & 0xffffu)) + fr.z * (float)u.z;
        float po = bf2f((ushort_t)(xc.y >> 16))     + fr.w * (float)u.w;
        float ig = fsig(pi), fg = fsig(pf), gg = ftanh(pg), og = fsig(po);
        c_state = fg * c_state + ig * gg;
        float h = og * ftanh(c_state);
        int q = __float2int_rn(h * 127.0f);
        q = min(127, max(-127, q));
        h8[1 - (s & 1)][j] = (char)q;           // gates the barrier
        int t = time_idx(s, len, d);
        out[((size_t)b * 512 + t) * 512 + d * 256 + j] = h;

        // single lgkm-only barrier: h8 is double-buffered, reads of the
        // current buffer are drained by each wave's own lgkmcnt(0).
        lds_barrier();
    }
}

// ---------------------------------------------------------------------------
extern "C" void kernel_launch(void* const* d_in, const int* in_sizes, int n_in,
                              void* d_out, int out_size, void* d_ws, size_t ws_size,
                              hipStream_t stream) {
    (void)in_sizes; (void)n_in; (void)out_size;
    const float* x    = (const float*)d_in[0];
    const int*   lens = (const int*)d_in[1];
    const float* wihf = (const float*)d_in[2];
    const float* whhf = (const float*)d_in[3];
    const float* bihf = (const float*)d_in[4];
    const float* bhhf = (const float*)d_in[5];
    const float* wihb = (const float*)d_in[6];
    const float* whhb = (const float*)d_in[7];
    const float* bihb = (const float*)d_in[8];
    const float* bhhb = (const float*)d_in[9];
    float* out = (float*)d_out;

    char* ws = (char*)d_ws;
    ushort_t* xbf    = (ushort_t*)(ws + 0);          //  16,777,216 B
    ushort_t* wihbf  = (ushort_t*)(ws + 16777216);   //   1,048,576 B
    float*    biasv  = (float*)(ws + 17825792);      //       8,192 B
    int*      wmf    = (int*)(ws + 17833984);        //     524,288 B
    float*    fscale4= (float*)(ws + 18358272);      //       8,192 B
    ushort_t* xproj  = (ushort_t*)(ws + 18366464);   // 134,217,728 B
    const size_t REQ = 18366464 + 134217728ull;
    if (ws_size < REQ) {
        fprintf(stderr, "kernel_launch: ws too small: %zu < %zu\n", ws_size, REQ);
    }

    k_f2bf<<<8192, 256, 0, stream>>>(x, xbf, 8388608);
    k_wih<<<dim3(256, 2), 256, 0, stream>>>(wihf, wihb, wihbf);
    k_bias<<<8, 256, 0, stream>>>(bihf, bhhf, bihb, bhhb, biasv);
    k_quant<<<512, 256, 0, stream>>>(whhf, whhb, wmf, fscale4);
    k_gemm<<<dim3(8, 256, 2), 256, 0, stream>>>(xbf, wihbf, biasv, xproj);
    k_rec<<<dim3(64, 2), 256, 0, stream>>>(xproj, wmf, fscale4, lens, out);
}

// Round 5
// 543.485 us; speedup vs baseline: 1.1390x; 1.1390x over previous
//
#include <hip/hip_runtime.h>
#include <cstdio>

// ---------------------------------------------------------------------------
// BiLSTM  B=64, T=512, D=256, H=256
//   P0: x -> bf16; Wih -> bf16 gate-permuted rows; bias vectors; Whh -> int8
//       packed into mfma_i32_16x16x64_i8 A-fragment order.
//   P1: MFMA bf16 GEMM -> xproj[d][b*512+t][j*4+gate]
//   P2: recurrence: 128 WGs (64 b x 2 dir) x 512 thr, 8 waves (R2 structure,
//       the measured best: 395us). R8 polish: time loop unrolled x2 so
//       h8 buffer indices are compile-time constants and the x-prefetch
//       ring needs no register rotation (true 2-step vmcnt slack);
//       time_idx replaced by uniform SALU offsets. R4's 4-wave variant
//       (467us) proved the step is latency-bound under lockstep: 2
//       waves/SIMD are needed to hide ds/mfma/tail latency; register
//       capacity (128 pinned dwords/thread) forbids more.
// ---------------------------------------------------------------------------

typedef unsigned short ushort_t;
typedef __attribute__((ext_vector_type(8))) short short8;
typedef __attribute__((ext_vector_type(4))) float f32x4;
typedef __attribute__((ext_vector_type(4))) int i32x4;

__device__ __forceinline__ ushort_t f2bf(float f) {
    union { float f; unsigned u; } v; v.f = f;
    unsigned r = v.u + 0x7fffu + ((v.u >> 16) & 1u);
    return (ushort_t)(r >> 16);
}
__device__ __forceinline__ float bf2f(ushort_t h) {
    union { unsigned u; float f; } v; v.u = ((unsigned)h) << 16;
    return v.f;
}

__device__ __forceinline__ float fexp2(float x) {
#if __has_builtin(__builtin_amdgcn_exp2f)
    return __builtin_amdgcn_exp2f(x);
#else
    return exp2f(x);
#endif
}
__device__ __forceinline__ float frcp(float x) {
#if __has_builtin(__builtin_amdgcn_rcpf)
    return __builtin_amdgcn_rcpf(x);
#else
    return 1.0f / x;
#endif
}
__device__ __forceinline__ float fsig(float x) {
    return frcp(1.0f + fexp2(-1.44269504089f * x));
}
__device__ __forceinline__ float ftanh(float x) {
    float e = fexp2(2.88539008178f * x);
    return 1.0f - 2.0f * frcp(e + 1.0f);
}

// LDS-only barrier: drain lgkm (LDS ops) but NOT vmcnt.
__device__ __forceinline__ void lds_barrier() {
    asm volatile("s_waitcnt lgkmcnt(0)\n\ts_barrier" ::: "memory");
}

// ---------------------------------------------------------------------------
// P0a: fp32 -> bf16 (n multiple of 4)
__global__ __launch_bounds__(256) void k_f2bf(const float* __restrict__ in,
                                              ushort_t* __restrict__ out, int n) {
    int i = (blockIdx.x * 256 + threadIdx.x) * 4;
    if (i + 3 < n) {
        float4 v = *(const float4*)&in[i];
        ushort4 o;
        o.x = f2bf(v.x); o.y = f2bf(v.y); o.z = f2bf(v.z); o.w = f2bf(v.w);
        *(ushort4*)&out[i] = o;
    }
}

// P0b: Wih fp32 -> bf16 with gate-permuted ROW order:
//   dst[d][(n&255)*4 + (n>>8)][k] = src_d[n][k]
__global__ __launch_bounds__(256) void k_wih(const float* __restrict__ wihf,
                                             const float* __restrict__ wihb,
                                             ushort_t* __restrict__ dst) {
    int d = blockIdx.y;
    int n = blockIdx.x * 4 + (threadIdx.x >> 6);   // 0..1023
    int l = threadIdx.x & 63;
    const float* src = (d ? wihb : wihf) + (size_t)n * 256;
    float4 v = *(const float4*)&src[l * 4];
    int np = (n & 255) * 4 + (n >> 8);
    ushort4 o;
    o.x = f2bf(v.x); o.y = f2bf(v.y); o.z = f2bf(v.z); o.w = f2bf(v.w);
    *(ushort4*)&dst[((size_t)d * 1024 + np) * 256 + l * 4] = o;
}

// P0c: permuted bias vectors bv[d][(n&255)*4 + (n>>8)] = bih_d[n] + bhh_d[n]
__global__ __launch_bounds__(256) void k_bias(const float* __restrict__ bihf,
                                              const float* __restrict__ bhhf,
                                              const float* __restrict__ bihb,
                                              const float* __restrict__ bhhb,
                                              float* __restrict__ bv) {
    int i = blockIdx.x * 256 + threadIdx.x;   // 0..2047
    int d = i >> 10, n = i & 1023;
    float s = d ? (bihb[n] + bhhb[n]) : (bihf[n] + bhhf[n]);
    bv[d * 1024 + (n & 255) * 4 + (n >> 8)] = s;
}

// P0d: quantize Whh rows to int8, packed into mfma_i32_16x16x64_i8
// A-fragment order. Fragment (Mt,Kt): lane l holds row Mt*16+(l&15),
// k = Kt*64 + (l>>4)*16 + {0..15} (4 dwords, byte0 = lowest k).
//   Mt = row_p>>4, rl = row_p&15, Kt = kc>>4, lg = (kc>>2)&3, dw = kc&3
//   wmf[d*65536 + ((Mt*4+Kt)*64 + lg*16 + rl)*4 + dw] = packed
__global__ __launch_bounds__(256) void k_quant(const float* __restrict__ whhf,
                                               const float* __restrict__ whhb,
                                               int* __restrict__ wmf,
                                               float* __restrict__ fscale4) {
    int rowg = blockIdx.x * 4 + (threadIdx.x >> 6);   // 0..2047
    int l = threadIdx.x & 63;                          // = kc
    int d = rowg >> 10;
    int row = rowg & 1023;
    const float* W = (d ? whhb : whhf) + (size_t)row * 256;
    float4 v = *(const float4*)&W[l * 4];
    float m = fmaxf(fmaxf(fabsf(v.x), fabsf(v.y)), fmaxf(fabsf(v.z), fabsf(v.w)));
    #pragma unroll
    for (int off = 32; off > 0; off >>= 1) m = fmaxf(m, __shfl_xor(m, off));
    float inv = (m > 0.0f) ? (127.0f / m) : 0.0f;
    int q0 = __float2int_rn(v.x * inv);
    int q1 = __float2int_rn(v.y * inv);
    int q2 = __float2int_rn(v.z * inv);
    int q3 = __float2int_rn(v.w * inv);
    q0 = min(127, max(-127, q0)); q1 = min(127, max(-127, q1));
    q2 = min(127, max(-127, q2)); q3 = min(127, max(-127, q3));
    int packed = (q0 & 255) | ((q1 & 255) << 8) | ((q2 & 255) << 16) | ((q3 & 255) << 24);
    int j = row & 255, gate = row >> 8;
    int row_p = j * 4 + gate;
    int Mt = row_p >> 4, rl = row_p & 15;
    int Kt = l >> 4, lg = (l >> 2) & 3, dw = l & 3;
    wmf[d * 65536 + ((Mt * 4 + Kt) * 64 + lg * 16 + rl) * 4 + dw] = packed;
    if (l == 0) fscale4[d * 1024 + row_p] = m / (127.0f * 127.0f);
}

// ---------------------------------------------------------------------------
// P1: bf16 GEMM (contiguous epilogue; B rows pre-permuted).
#define LDSOFF(r, kc) ((r) * 32 + ((((kc) + ((r) >> 1)) & 3) * 8))

__global__ __launch_bounds__(256) void k_gemm(const ushort_t* __restrict__ A,
                                              const ushort_t* __restrict__ Bw,
                                              const float* __restrict__ biasv,
                                              ushort_t* __restrict__ Xp) {
    const int dir = blockIdx.z;
    const ushort_t* Bmat = Bw + dir * 262144;
    const float* bv = biasv + dir * 1024;
    ushort_t* C = Xp + (size_t)dir * 33554432;
    const int tn = blockIdx.x;   // 0..7
    const int tm = blockIdx.y;   // 0..255
    const int tid = threadIdx.x;
    const int w = tid >> 6, l = tid & 63;
    const int wm = w & 1, wn = w >> 1;

    __shared__ ushort_t As[128 * 32];
    __shared__ ushort_t Bs[128 * 32];

    f32x4 acc[4][4];
    #pragma unroll
    for (int i = 0; i < 4; i++)
        #pragma unroll
        for (int jj = 0; jj < 4; jj++) acc[i][jj] = (f32x4){0.f, 0.f, 0.f, 0.f};

    const int r0 = tid >> 2, c0 = tid & 3;
    const int r1 = (tid + 256) >> 2, c1 = tid & 3;

    for (int kb = 0; kb < 8; kb++) {
        __syncthreads();
        {
            short8 a0 = *(const short8*)&A[((size_t)(tm * 128 + r0)) * 256 + kb * 32 + c0 * 8];
            short8 a1 = *(const short8*)&A[((size_t)(tm * 128 + r1)) * 256 + kb * 32 + c1 * 8];
            short8 b0 = *(const short8*)&Bmat[((size_t)(tn * 128 + r0)) * 256 + kb * 32 + c0 * 8];
            short8 b1 = *(const short8*)&Bmat[((size_t)(tn * 128 + r1)) * 256 + kb * 32 + c1 * 8];
            *(short8*)&As[LDSOFF(r0, c0)] = a0;
            *(short8*)&As[LDSOFF(r1, c1)] = a1;
            *(short8*)&Bs[LDSOFF(r0, c0)] = b0;
            *(short8*)&Bs[LDSOFF(r1, c1)] = b1;
        }
        __syncthreads();
        short8 af[4], bfr[4];
        const int q = l >> 4;
        #pragma unroll
        for (int mt = 0; mt < 4; mt++) {
            int rr = wm * 64 + mt * 16 + (l & 15);
            af[mt] = *(const short8*)&As[LDSOFF(rr, q)];
        }
        #pragma unroll
        for (int nt = 0; nt < 4; nt++) {
            int rr = wn * 64 + nt * 16 + (l & 15);
            bfr[nt] = *(const short8*)&Bs[LDSOFF(rr, q)];
        }
        #pragma unroll
        for (int mt = 0; mt < 4; mt++)
            #pragma unroll
            for (int nt = 0; nt < 4; nt++)
                acc[mt][nt] = __builtin_amdgcn_mfma_f32_16x16x32_bf16(
                    af[mt], bfr[nt], acc[mt][nt], 0, 0, 0);
    }
    #pragma unroll
    for (int nt = 0; nt < 4; nt++) {
        int n = tn * 128 + wn * 64 + nt * 16 + (l & 15);
        float bn = bv[n];
        #pragma unroll
        for (int mt = 0; mt < 4; mt++) {
            #pragma unroll
            for (int rr = 0; rr < 4; rr++) {
                int m = tm * 128 + wm * 64 + mt * 16 + (l >> 4) * 4 + rr;
                C[(size_t)m * 1024 + n] = f2bf(acc[mt][nt][rr] + bn);
            }
        }
    }
}

// ---------------------------------------------------------------------------
// P2: recurrence. grid (64 batch, 2 dir) x 512 threads (8 waves).
// Wave w owns M-tiles w*8..w*8+7 (units w*32..w*32+31).
// Lane l: rg = l>>4, til = l&7; active lanes ((l&15)<8) each own
// unit j = (w*8+til)*4 + rg and hold its persistent c_state.
__global__ __launch_bounds__(512, 2) void k_rec(const ushort_t* __restrict__ xproj,
                                                const int* __restrict__ wmf,
                                                const float* __restrict__ fscale4,
                                                const int* __restrict__ lens,
                                                float* __restrict__ out) {
    const int b = blockIdx.x, d = blockIdx.y;
    const int tid = threadIdx.x;
    const int w = tid >> 6, l = tid & 63;
    int len = lens[b];
    if (len < 1) len = 1;
    if (len > 512) len = 512;
    const int lenm1 = len - 1;
    const bool dneg = (d != 0);
    const ushort_t* xp = xproj + ((size_t)d * 64 + b) * 524288;  // 512*1024

    const int rg = l >> 4;            // 0..3
    const int rg16 = rg * 16;
    const int til = l & 7;
    const bool act = (l & 15) < 8;
    const int j = (w * 8 + til) * 4 + rg;   // unit 0..255

    // 32 A-fragments (128 dwords) pinned in VGPRs.
    i32x4 wf[8][4];
    const int* wb = wmf + d * 65536;
    #pragma unroll
    for (int i = 0; i < 8; i++)
        #pragma unroll
        for (int kt = 0; kt < 4; kt++)
            wf[i][kt] = *(const i32x4*)&wb[(((w * 8 + i) * 4 + kt) * 64 + l) * 4];
    #pragma unroll
    for (int i = 0; i < 8; i++)
        #pragma unroll
        for (int kt = 0; kt < 4; kt++)
            asm volatile("" : "+v"(wf[i][kt]));

    float4 fr = *(const float4*)&fscale4[d * 1024 + 4 * j];   // loop-invariant

    __shared__ char h8[2][256] __attribute__((aligned(16)));
    if (tid < 64) ((int*)h8)[tid] = 0;   // zero h8[0]

    // zero-fill this direction's half for t in [len, 512)
    {
        float4 z = {0.f, 0.f, 0.f, 0.f};
        int total4 = (512 - len) * 64;
        for (int i = tid; i < total4; i += 512) {
            int t = len + (i >> 6);
            int c4 = i & 63;
            *(float4*)&out[((size_t)b * 512 + t) * 512 + d * 256 + c4 * 4] = z;
        }
    }
    __syncthreads();

    float c_state = 0.0f;
    const i32x4 z4 = {0, 0, 0, 0};
    // lane-fixed byte pointers; per-step offsets are wave-uniform t*2048.
    const char* const xpl = (const char*)(xp + 4 * j);             // x row t: +t*2048
    char* const outl = (char*)(out + (size_t)b * 262144 + d * 256 + j);  // row t: +t*2048

    // x values for steps s and s+1 (loaded 2 steps ahead, no rotation movs).
    uint2 xe = *(const uint2*)(xpl + (size_t)(dneg ? lenm1 : 0) * 2048);
    uint2 xo;
    {
        int sc = (1 < lenm1) ? 1 : lenm1;
        xo = *(const uint2*)(xpl + (size_t)(dneg ? (lenm1 - sc) : sc) * 2048);
    }

    // One recurrence step at compile-time h8 parity (RB -> read, WB -> write).
    // XREG holds x for this step; it is reloaded with step S+2's row.
#define REC_STEP(RB, WB, XREG, S)                                              \
    do {                                                                       \
        const char* hbp = (const char*)h8[RB];                                 \
        i32x4 h0 = *(const i32x4*)(hbp + rg16);                                \
        i32x4 h1 = *(const i32x4*)(hbp + 64 + rg16);                           \
        i32x4 h2 = *(const i32x4*)(hbp + 128 + rg16);                          \
        i32x4 h3 = *(const i32x4*)(hbp + 192 + rg16);                          \
        uint2 xc = XREG;                                                       \
        {                                                                      \
            int sc2 = (S) + 2; if (sc2 > lenm1) sc2 = lenm1;                   \
            int t2 = dneg ? (lenm1 - sc2) : sc2;                               \
            XREG = *(const uint2*)(xpl + (size_t)t2 * 2048);                   \
        }                                                                      \
        i32x4 acc[8];                                                          \
        _Pragma("unroll")                                                      \
        for (int i = 0; i < 8; i++)                                            \
            acc[i] = __builtin_amdgcn_mfma_i32_16x16x64_i8(wf[i][0], h0, z4, 0, 0, 0); \
        _Pragma("unroll")                                                      \
        for (int i = 0; i < 8; i++)                                            \
            acc[i] = __builtin_amdgcn_mfma_i32_16x16x64_i8(wf[i][1], h1, acc[i], 0, 0, 0); \
        _Pragma("unroll")                                                      \
        for (int i = 0; i < 8; i++)                                            \
            acc[i] = __builtin_amdgcn_mfma_i32_16x16x64_i8(wf[i][2], h2, acc[i], 0, 0, 0); \
        _Pragma("unroll")                                                      \
        for (int i = 0; i < 8; i++)                                            \
            acc[i] = __builtin_amdgcn_mfma_i32_16x16x64_i8(wf[i][3], h3, acc[i], 0, 0, 0); \
        if (act) {                                                             \
            i32x4 q0 = (til & 1) ? acc[1] : acc[0];                            \
            i32x4 q1 = (til & 1) ? acc[3] : acc[2];                            \
            i32x4 q2 = (til & 1) ? acc[5] : acc[4];                            \
            i32x4 q3 = (til & 1) ? acc[7] : acc[6];                            \
            i32x4 r0 = (til & 2) ? q1 : q0;                                    \
            i32x4 r1 = (til & 2) ? q3 : q2;                                    \
            i32x4 u  = (til & 4) ? r1 : r0;                                    \
            float pi = bf2f((ushort_t)(xc.x & 0xffffu)) + fr.x * (float)u.x;   \
            float pf = bf2f((ushort_t)(xc.x >> 16))     + fr.y * (float)u.y;   \
            float pg = bf2f((ushort_t)(xc.y & 0xffffu)) + fr.z * (float)u.z;   \
            float po = bf2f((ushort_t)(xc.y >> 16))     + fr.w * (float)u.w;   \
            float ig = fsig(pi), fg = fsig(pf), gg = ftanh(pg), og = fsig(po); \
            c_state = fg * c_state + ig * gg;                                  \
            float h = og * ftanh(c_state);                                     \
            int qq = __float2int_rn(h * 127.0f);                               \
            qq = min(127, max(-127, qq));                                      \
            h8[WB][j] = (char)qq;                                              \
            int t = dneg ? (lenm1 - (S)) : (S);                                \
            *(float*)(outl + (size_t)t * 2048) = h;                            \
        }                                                                      \
        lds_barrier();                                                         \
    } while (0)

    int s = 0;
    for (; s + 1 < len; s += 2) {
        REC_STEP(0, 1, xe, s);
        REC_STEP(1, 0, xo, s + 1);
    }
    if (len & 1) {
        REC_STEP(0, 1, xe, s);
    }
#undef REC_STEP
}

// ---------------------------------------------------------------------------
extern "C" void kernel_launch(void* const* d_in, const int* in_sizes, int n_in,
                              void* d_out, int out_size, void* d_ws, size_t ws_size,
                              hipStream_t stream) {
    (void)in_sizes; (void)n_in; (void)out_size;
    const float* x    = (const float*)d_in[0];
    const int*   lens = (const int*)d_in[1];
    const float* wihf = (const float*)d_in[2];
    const float* whhf = (const float*)d_in[3];
    const float* bihf = (const float*)d_in[4];
    const float* bhhf = (const float*)d_in[5];
    const float* wihb = (const float*)d_in[6];
    const float* whhb = (const float*)d_in[7];
    const float* bihb = (const float*)d_in[8];
    const float* bhhb = (const float*)d_in[9];
    float* out = (float*)d_out;

    char* ws = (char*)d_ws;
    ushort_t* xbf    = (ushort_t*)(ws + 0);          //  16,777,216 B
    ushort_t* wihbf  = (ushort_t*)(ws + 16777216);   //   1,048,576 B
    float*    biasv  = (float*)(ws + 17825792);      //       8,192 B
    int*      wmf    = (int*)(ws + 17833984);        //     524,288 B
    float*    fscale4= (float*)(ws + 18358272);      //       8,192 B
    ushort_t* xproj  = (ushort_t*)(ws + 18366464);   // 134,217,728 B
    const size_t REQ = 18366464 + 134217728ull;
    if (ws_size < REQ) {
        fprintf(stderr, "kernel_launch: ws too small: %zu < %zu\n", ws_size, REQ);
    }

    k_f2bf<<<8192, 256, 0, stream>>>(x, xbf, 8388608);
    k_wih<<<dim3(256, 2), 256, 0, stream>>>(wihf, wihb, wihbf);
    k_bias<<<8, 256, 0, stream>>>(bihf, bhhf, bihb, bhhb, biasv);
    k_quant<<<512, 256, 0, stream>>>(whhf, whhb, wmf, fscale4);
    k_gemm<<<dim3(8, 256, 2), 256, 0, stream>>>(xbf, wihbf, biasv, xproj);
    k_rec<<<dim3(64, 2), 512, 0, stream>>>(xproj, wmf, fscale4, lens, out);
}

// Round 7
// 539.743 us; speedup vs baseline: 1.1469x; 1.0069x over previous
//
#include <hip/hip_runtime.h>
#include <cstdio>

// ---------------------------------------------------------------------------
// BiLSTM  B=64, T=512, D=256, H=256
//   P0: x -> bf16; Wih -> bf16 gate-permuted rows; bias vectors; Whh -> int8
//       packed into mfma_i32_16x16x64_i8 A-fragment order.
//   P1: MFMA bf16 GEMM -> xproj[d][b*512+t][j*4+gate]. R9/R10: staging via
//       global_load_lds dwordx4 with EXPLICITLY wave-uniform LDS base
//       (hardware writes lane l at base + l*16 -- m104/m108 idiom); the
//       LDSOFF bank-conflict swizzle is preserved by pre-swizzling the
//       global SOURCE col-chunk (linear LDS dest + inverse-swz source +
//       swz read). Staged LDS bytes identical to the reg-staged R8 kernel.
//   P2: recurrence: 128 WGs (64 b x 2 dir) x 512 thr, 8 waves — unchanged
//       R8 champion (379us): x2-unrolled time loop, compile-time h8 parity,
//       int8 matvec on the matrix pipe, single lgkm-only barrier per step.
// ---------------------------------------------------------------------------

typedef unsigned short ushort_t;
typedef __attribute__((ext_vector_type(8))) short short8;
typedef __attribute__((ext_vector_type(4))) float f32x4;
typedef __attribute__((ext_vector_type(4))) int i32x4;

__device__ __forceinline__ ushort_t f2bf(float f) {
    union { float f; unsigned u; } v; v.f = f;
    unsigned r = v.u + 0x7fffu + ((v.u >> 16) & 1u);
    return (ushort_t)(r >> 16);
}
__device__ __forceinline__ float bf2f(ushort_t h) {
    union { unsigned u; float f; } v; v.u = ((unsigned)h) << 16;
    return v.f;
}

__device__ __forceinline__ float fexp2(float x) {
#if __has_builtin(__builtin_amdgcn_exp2f)
    return __builtin_amdgcn_exp2f(x);
#else
    return exp2f(x);
#endif
}
__device__ __forceinline__ float frcp(float x) {
#if __has_builtin(__builtin_amdgcn_rcpf)
    return __builtin_amdgcn_rcpf(x);
#else
    return 1.0f / x;
#endif
}
__device__ __forceinline__ float fsig(float x) {
    return frcp(1.0f + fexp2(-1.44269504089f * x));
}
__device__ __forceinline__ float ftanh(float x) {
    float e = fexp2(2.88539008178f * x);
    return 1.0f - 2.0f * frcp(e + 1.0f);
}

// LDS-only barrier: drain lgkm (LDS ops) but NOT vmcnt.
__device__ __forceinline__ void lds_barrier() {
    asm volatile("s_waitcnt lgkmcnt(0)\n\ts_barrier" ::: "memory");
}

// Async global->LDS 16B. lds base must be wave-uniform; HW writes lane l's
// 16B at base + l*16 (measured m104/m108). Size arg must be a literal.
__device__ __forceinline__ void async_load16(const void* g, void* l) {
    __builtin_amdgcn_global_load_lds(
        (const __attribute__((address_space(1))) void*)g,
        (__attribute__((address_space(3))) void*)l, 16, 0, 0);
}

// ---------------------------------------------------------------------------
// P0a: fp32 -> bf16 (n multiple of 4)
__global__ __launch_bounds__(256) void k_f2bf(const float* __restrict__ in,
                                              ushort_t* __restrict__ out, int n) {
    int i = (blockIdx.x * 256 + threadIdx.x) * 4;
    if (i + 3 < n) {
        float4 v = *(const float4*)&in[i];
        ushort4 o;
        o.x = f2bf(v.x); o.y = f2bf(v.y); o.z = f2bf(v.z); o.w = f2bf(v.w);
        *(ushort4*)&out[i] = o;
    }
}

// P0b: Wih fp32 -> bf16 with gate-permuted ROW order:
//   dst[d][(n&255)*4 + (n>>8)][k] = src_d[n][k]
__global__ __launch_bounds__(256) void k_wih(const float* __restrict__ wihf,
                                             const float* __restrict__ wihb,
                                             ushort_t* __restrict__ dst) {
    int d = blockIdx.y;
    int n = blockIdx.x * 4 + (threadIdx.x >> 6);   // 0..1023
    int l = threadIdx.x & 63;
    const float* src = (d ? wihb : wihf) + (size_t)n * 256;
    float4 v = *(const float4*)&src[l * 4];
    int np = (n & 255) * 4 + (n >> 8);
    ushort4 o;
    o.x = f2bf(v.x); o.y = f2bf(v.y); o.z = f2bf(v.z); o.w = f2bf(v.w);
    *(ushort4*)&dst[((size_t)d * 1024 + np) * 256 + l * 4] = o;
}

// P0c: permuted bias vectors bv[d][(n&255)*4 + (n>>8)] = bih_d[n] + bhh_d[n]
__global__ __launch_bounds__(256) void k_bias(const float* __restrict__ bihf,
                                              const float* __restrict__ bhhf,
                                              const float* __restrict__ bihb,
                                              const float* __restrict__ bhhb,
                                              float* __restrict__ bv) {
    int i = blockIdx.x * 256 + threadIdx.x;   // 0..2047
    int d = i >> 10, n = i & 1023;
    float s = d ? (bihb[n] + bhhb[n]) : (bihf[n] + bhhf[n]);
    bv[d * 1024 + (n & 255) * 4 + (n >> 8)] = s;
}

// P0d: quantize Whh rows to int8, packed into mfma_i32_16x16x64_i8
// A-fragment order. Fragment (Mt,Kt): lane l holds row Mt*16+(l&15),
// k = Kt*64 + (l>>4)*16 + {0..15} (4 dwords, byte0 = lowest k).
//   Mt = row_p>>4, rl = row_p&15, Kt = kc>>4, lg = (kc>>2)&3, dw = kc&3
//   wmf[d*65536 + ((Mt*4+Kt)*64 + lg*16 + rl)*4 + dw] = packed
__global__ __launch_bounds__(256) void k_quant(const float* __restrict__ whhf,
                                               const float* __restrict__ whhb,
                                               int* __restrict__ wmf,
                                               float* __restrict__ fscale4) {
    int rowg = blockIdx.x * 4 + (threadIdx.x >> 6);   // 0..2047
    int l = threadIdx.x & 63;                          // = kc
    int d = rowg >> 10;
    int row = rowg & 1023;
    const float* W = (d ? whhb : whhf) + (size_t)row * 256;
    float4 v = *(const float4*)&W[l * 4];
    float m = fmaxf(fmaxf(fabsf(v.x), fabsf(v.y)), fmaxf(fabsf(v.z), fabsf(v.w)));
    #pragma unroll
    for (int off = 32; off > 0; off >>= 1) m = fmaxf(m, __shfl_xor(m, off));
    float inv = (m > 0.0f) ? (127.0f / m) : 0.0f;
    int q0 = __float2int_rn(v.x * inv);
    int q1 = __float2int_rn(v.y * inv);
    int q2 = __float2int_rn(v.z * inv);
    int q3 = __float2int_rn(v.w * inv);
    q0 = min(127, max(-127, q0)); q1 = min(127, max(-127, q1));
    q2 = min(127, max(-127, q2)); q3 = min(127, max(-127, q3));
    int packed = (q0 & 255) | ((q1 & 255) << 8) | ((q2 & 255) << 16) | ((q3 & 255) << 24);
    int j = row & 255, gate = row >> 8;
    int row_p = j * 4 + gate;
    int Mt = row_p >> 4, rl = row_p & 15;
    int Kt = l >> 4, lg = (l >> 2) & 3, dw = l & 3;
    wmf[d * 65536 + ((Mt * 4 + Kt) * 64 + lg * 16 + rl) * 4 + dw] = packed;
    if (l == 0) fscale4[d * 1024 + row_p] = m / (127.0f * 127.0f);
}

// ---------------------------------------------------------------------------
// P1: bf16 GEMM. Staging via global_load_lds with wave-uniform LDS base:
// wave wv covers bytes wv*1024 .. wv*1024+1023 of each half-tile (lane l
// at +l*16), i.e. rows wv*16..wv*16+15, chunk layout linear. The data
// loaded for LDS chunk cb of row r is source chunk (cb - (r>>1))&3, so
// the staged bytes equal the old LDSOFF-swizzled layout; the reader and
// epilogue are unchanged.
#define LDSOFF(r, kc) ((r) * 32 + ((((kc) + ((r) >> 1)) & 3) * 8))

__global__ __launch_bounds__(256) void k_gemm(const ushort_t* __restrict__ A,
                                              const ushort_t* __restrict__ Bw,
                                              const float* __restrict__ biasv,
                                              ushort_t* __restrict__ Xp) {
    const int dir = blockIdx.z;
    const ushort_t* Bmat = Bw + dir * 262144;
    const float* bv = biasv + dir * 1024;
    ushort_t* C = Xp + (size_t)dir * 33554432;
    const int tn = blockIdx.x;   // 0..7
    const int tm = blockIdx.y;   // 0..255
    const int tid = threadIdx.x;
    const int w = tid >> 6, l = tid & 63;
    const int wm = w & 1, wn = w >> 1;

    __shared__ ushort_t As[128 * 32];
    __shared__ ushort_t Bs[128 * 32];

    f32x4 acc[4][4];
    #pragma unroll
    for (int i = 0; i < 4; i++)
        #pragma unroll
        for (int jj = 0; jj < 4; jj++) acc[i][jj] = (f32x4){0.f, 0.f, 0.f, 0.f};

    // Staging geometry: thread tid covers rows {r0, r0+64}, LDS col-chunk cb.
    // Source col-chunk cs = (cb - (r0>>1)) & 3 (same for both row halves).
    const int r0 = tid >> 2, cb = tid & 3;
    const int cs = (cb - (r0 >> 1)) & 3;
    const ushort_t* Arow0 = &A[(size_t)(tm * 128 + r0) * 256 + cs * 8];
    const ushort_t* Arow1 = Arow0 + (size_t)64 * 256;
    const ushort_t* Brow0 = &Bmat[(size_t)(tn * 128 + r0) * 256 + cs * 8];
    const ushort_t* Brow1 = Brow0 + (size_t)64 * 256;
    // Wave-uniform LDS bases: lane 0 of wave wv writes byte wv*1024 (half 0)
    // and 4096 + wv*1024 (half 1); HW places lane l at +l*16.
    ushort_t* const ldsA0 = &As[w * 512];
    ushort_t* const ldsA1 = &As[2048 + w * 512];
    ushort_t* const ldsB0 = &Bs[w * 512];
    ushort_t* const ldsB1 = &Bs[2048 + w * 512];

    for (int kb = 0; kb < 8; kb++) {
        __syncthreads();   // previous iteration's LDS reads done
        async_load16(Arow0 + kb * 32, ldsA0);
        async_load16(Arow1 + kb * 32, ldsA1);
        async_load16(Brow0 + kb * 32, ldsB0);
        async_load16(Brow1 + kb * 32, ldsB1);
        asm volatile("s_waitcnt vmcnt(0)" ::: "memory");
        __syncthreads();
        short8 af[4], bfr[4];
        const int q = l >> 4;
        #pragma unroll
        for (int mt = 0; mt < 4; mt++) {
            int rr = wm * 64 + mt * 16 + (l & 15);
            af[mt] = *(const short8*)&As[LDSOFF(rr, q)];
        }
        #pragma unroll
        for (int nt = 0; nt < 4; nt++) {
            int rr = wn * 64 + nt * 16 + (l & 15);
            bfr[nt] = *(const short8*)&Bs[LDSOFF(rr, q)];
        }
        #pragma unroll
        for (int mt = 0; mt < 4; mt++)
            #pragma unroll
            for (int nt = 0; nt < 4; nt++)
                acc[mt][nt] = __builtin_amdgcn_mfma_f32_16x16x32_bf16(
                    af[mt], bfr[nt], acc[mt][nt], 0, 0, 0);
    }
    #pragma unroll
    for (int nt = 0; nt < 4; nt++) {
        int n = tn * 128 + wn * 64 + nt * 16 + (l & 15);
        float bn = bv[n];
        #pragma unroll
        for (int mt = 0; mt < 4; mt++) {
            #pragma unroll
            for (int rr = 0; rr < 4; rr++) {
                int m = tm * 128 + wm * 64 + mt * 16 + (l >> 4) * 4 + rr;
                C[(size_t)m * 1024 + n] = f2bf(acc[mt][nt][rr] + bn);
            }
        }
    }
}

// ---------------------------------------------------------------------------
// P2: recurrence. grid (64 batch, 2 dir) x 512 threads (8 waves).
// Wave w owns M-tiles w*8..w*8+7 (units w*32..w*32+31).
// Lane l: rg = l>>4, til = l&7; active lanes ((l&15)<8) each own
// unit j = (w*8+til)*4 + rg and hold its persistent c_state.
__global__ __launch_bounds__(512, 2) void k_rec(const ushort_t* __restrict__ xproj,
                                                const int* __restrict__ wmf,
                                                const float* __restrict__ fscale4,
                                                const int* __restrict__ lens,
                                                float* __restrict__ out) {
    const int b = blockIdx.x, d = blockIdx.y;
    const int tid = threadIdx.x;
    const int w = tid >> 6, l = tid & 63;
    int len = lens[b];
    if (len < 1) len = 1;
    if (len > 512) len = 512;
    const int lenm1 = len - 1;
    const bool dneg = (d != 0);
    const ushort_t* xp = xproj + ((size_t)d * 64 + b) * 524288;  // 512*1024

    const int rg = l >> 4;            // 0..3
    const int rg16 = rg * 16;
    const int til = l & 7;
    const bool act = (l & 15) < 8;
    const int j = (w * 8 + til) * 4 + rg;   // unit 0..255

    // 32 A-fragments (128 dwords) pinned in VGPRs.
    i32x4 wf[8][4];
    const int* wb = wmf + d * 65536;
    #pragma unroll
    for (int i = 0; i < 8; i++)
        #pragma unroll
        for (int kt = 0; kt < 4; kt++)
            wf[i][kt] = *(const i32x4*)&wb[(((w * 8 + i) * 4 + kt) * 64 + l) * 4];
    #pragma unroll
    for (int i = 0; i < 8; i++)
        #pragma unroll
        for (int kt = 0; kt < 4; kt++)
            asm volatile("" : "+v"(wf[i][kt]));

    float4 fr = *(const float4*)&fscale4[d * 1024 + 4 * j];   // loop-invariant

    __shared__ char h8[2][256] __attribute__((aligned(16)));
    if (tid < 64) ((int*)h8)[tid] = 0;   // zero h8[0]

    // zero-fill this direction's half for t in [len, 512)
    {
        float4 z = {0.f, 0.f, 0.f, 0.f};
        int total4 = (512 - len) * 64;
        for (int i = tid; i < total4; i += 512) {
            int t = len + (i >> 6);
            int c4 = i & 63;
            *(float4*)&out[((size_t)b * 512 + t) * 512 + d * 256 + c4 * 4] = z;
        }
    }
    __syncthreads();

    float c_state = 0.0f;
    const i32x4 z4 = {0, 0, 0, 0};
    // lane-fixed byte pointers; per-step offsets are wave-uniform t*2048.
    const char* const xpl = (const char*)(xp + 4 * j);             // x row t: +t*2048
    char* const outl = (char*)(out + (size_t)b * 262144 + d * 256 + j);  // row t: +t*2048

    // x values for steps s and s+1 (loaded 2 steps ahead, no rotation movs).
    uint2 xe = *(const uint2*)(xpl + (size_t)(dneg ? lenm1 : 0) * 2048);
    uint2 xo;
    {
        int sc = (1 < lenm1) ? 1 : lenm1;
        xo = *(const uint2*)(xpl + (size_t)(dneg ? (lenm1 - sc) : sc) * 2048);
    }

    // One recurrence step at compile-time h8 parity (RB -> read, WB -> write).
    // XREG holds x for this step; it is reloaded with step S+2's row.
#define REC_STEP(RB, WB, XREG, S)                                              \
    do {                                                                       \
        const char* hbp = (const char*)h8[RB];                                 \
        i32x4 h0 = *(const i32x4*)(hbp + rg16);                                \
        i32x4 h1 = *(const i32x4*)(hbp + 64 + rg16);                           \
        i32x4 h2 = *(const i32x4*)(hbp + 128 + rg16);                          \
        i32x4 h3 = *(const i32x4*)(hbp + 192 + rg16);                          \
        uint2 xc = XREG;                                                       \
        {                                                                      \
            int sc2 = (S) + 2; if (sc2 > lenm1) sc2 = lenm1;                   \
            int t2 = dneg ? (lenm1 - sc2) : sc2;                               \
            XREG = *(const uint2*)(xpl + (size_t)t2 * 2048);                   \
        }                                                                      \
        i32x4 acc[8];                                                          \
        _Pragma("unroll")                                                      \
        for (int i = 0; i < 8; i++)                                            \
            acc[i] = __builtin_amdgcn_mfma_i32_16x16x64_i8(wf[i][0], h0, z4, 0, 0, 0); \
        _Pragma("unroll")                                                      \
        for (int i = 0; i < 8; i++)                                            \
            acc[i] = __builtin_amdgcn_mfma_i32_16x16x64_i8(wf[i][1], h1, acc[i], 0, 0, 0); \
        _Pragma("unroll")                                                      \
        for (int i = 0; i < 8; i++)                                            \
            acc[i] = __builtin_amdgcn_mfma_i32_16x16x64_i8(wf[i][2], h2, acc[i], 0, 0, 0); \
        _Pragma("unroll")                                                      \
        for (int i = 0; i < 8; i++)                                            \
            acc[i] = __builtin_amdgcn_mfma_i32_16x16x64_i8(wf[i][3], h3, acc[i], 0, 0, 0); \
        if (act) {                                                             \
            i32x4 q0 = (til & 1) ? acc[1] : acc[0];                            \
            i32x4 q1 = (til & 1) ? acc[3] : acc[2];                            \
            i32x4 q2 = (til & 1) ? acc[5] : acc[4];                            \
            i32x4 q3 = (til & 1) ? acc[7] : acc[6];                            \
            i32x4 r0 = (til & 2) ? q1 : q0;                                    \
            i32x4 r1 = (til & 2) ? q3 : q2;                                    \
            i32x4 u  = (til & 4) ? r1 : r0;                                    \
            float pi = bf2f((ushort_t)(xc.x & 0xffffu)) + fr.x * (float)u.x;   \
            float pf = bf2f((ushort_t)(xc.x >> 16))     + fr.y * (float)u.y;   \
            float pg = bf2f((ushort_t)(xc.y & 0xffffu)) + fr.z * (float)u.z;   \
            float po = bf2f((ushort_t)(xc.y >> 16))     + fr.w * (float)u.w;   \
            float ig = fsig(pi), fg = fsig(pf), gg = ftanh(pg), og = fsig(po); \
            c_state = fg * c_state + ig * gg;                                  \
            float h = og * ftanh(c_state);                                     \
            int qq = __float2int_rn(h * 127.0f);                               \
            qq = min(127, max(-127, qq));                                      \
            h8[WB][j] = (char)qq;                                              \
            int t = dneg ? (lenm1 - (S)) : (S);                                \
            *(float*)(outl + (size_t)t * 2048) = h;                            \
        }                                                                      \
        lds_barrier();                                                         \
    } while (0)

    int s = 0;
    for (; s + 1 < len; s += 2) {
        REC_STEP(0, 1, xe, s);
        REC_STEP(1, 0, xo, s + 1);
    }
    if (len & 1) {
        REC_STEP(0, 1, xe, s);
    }
#undef REC_STEP
}

// ---------------------------------------------------------------------------
extern "C" void kernel_launch(void* const* d_in, const int* in_sizes, int n_in,
                              void* d_out, int out_size, void* d_ws, size_t ws_size,
                              hipStream_t stream) {
    (void)in_sizes; (void)n_in; (void)out_size;
    const float* x    = (const float*)d_in[0];
    const int*   lens = (const int*)d_in[1];
    const float* wihf = (const float*)d_in[2];
    const float* whhf = (const float*)d_in[3];
    const float* bihf = (const float*)d_in[4];
    const float* bhhf = (const float*)d_in[5];
    const float* wihb = (const float*)d_in[6];
    const float* whhb = (const float*)d_in[7];
    const float* bihb = (const float*)d_in[8];
    const float* bhhb = (const float*)d_in[9];
    float* out = (float*)d_out;

    char* ws = (char*)d_ws;
    ushort_t* xbf    = (ushort_t*)(ws + 0);          //  16,777,216 B
    ushort_t* wihbf  = (ushort_t*)(ws + 16777216);   //   1,048,576 B
    float*    biasv  = (float*)(ws + 17825792);      //       8,192 B
    int*      wmf    = (int*)(ws + 17833984);        //     524,288 B
    float*    fscale4= (float*)(ws + 18358272);      //       8,192 B
    ushort_t* xproj  = (ushort_t*)(ws + 18366464);   // 134,217,728 B
    const size_t REQ = 18366464 + 134217728ull;
    if (ws_size < REQ) {
        fprintf(stderr, "kernel_launch: ws too small: %zu < %zu\n", ws_size, REQ);
    }

    k_f2bf<<<8192, 256, 0, stream>>>(x, xbf, 8388608);
    k_wih<<<dim3(256, 2), 256, 0, stream>>>(wihf, wihb, wihbf);
    k_bias<<<8, 256, 0, stream>>>(bihf, bhhf, bihb, bhhb, biasv);
    k_quant<<<512, 256, 0, stream>>>(whhf, whhb, wmf, fscale4);
    k_gemm<<<dim3(8, 256, 2), 256, 0, stream>>>(xbf, wihbf, biasv, xproj);
    k_rec<<<dim3(64, 2), 512, 0, stream>>>(xproj, wmf, fscale4, lens, out);
}

// Round 8
// 520.020 us; speedup vs baseline: 1.1904x; 1.0379x over previous
//
#include <hip/hip_runtime.h>
#include <cstdio>

// ---------------------------------------------------------------------------
// BiLSTM  B=64, T=512, D=256, H=256
//   P0: x -> bf16; Wih -> bf16 gate-permuted rows; bias vectors; Whh -> int8
//       packed into mfma_i32_16x16x64_i8 A-fragment order.
//   P1: MFMA bf16 GEMM -> xproj[d][b*512+t][j*4+gate]. R11:
//       (a) length-aware tile skip: k_rec never reads rows t>=len (all
//           time_idx clamped), and lens avg ~256/512 -> ~44% of tiles dead;
//       (b) 2-deep double-buffered pipeline, counted vmcnt(4) (drain-0 only
//           at the tail) -- R7 proved drain-every-step hides nothing.
//       Staged bytes per computed tile identical to R8 (source pre-swizzle
//       preserves the LDSOFF layout; reader/epilogue unchanged).
//   P2: recurrence: 128 WGs (64 b x 2 dir) x 512 thr, 8 waves — unchanged
//       R8 champion (379us): x2-unrolled time loop, compile-time h8 parity,
//       int8 matvec on the matrix pipe, single lgkm-only barrier per step.
// ---------------------------------------------------------------------------

typedef unsigned short ushort_t;
typedef __attribute__((ext_vector_type(8))) short short8;
typedef __attribute__((ext_vector_type(4))) float f32x4;
typedef __attribute__((ext_vector_type(4))) int i32x4;

__device__ __forceinline__ ushort_t f2bf(float f) {
    union { float f; unsigned u; } v; v.f = f;
    unsigned r = v.u + 0x7fffu + ((v.u >> 16) & 1u);
    return (ushort_t)(r >> 16);
}
__device__ __forceinline__ float bf2f(ushort_t h) {
    union { unsigned u; float f; } v; v.u = ((unsigned)h) << 16;
    return v.f;
}

__device__ __forceinline__ float fexp2(float x) {
#if __has_builtin(__builtin_amdgcn_exp2f)
    return __builtin_amdgcn_exp2f(x);
#else
    return exp2f(x);
#endif
}
__device__ __forceinline__ float frcp(float x) {
#if __has_builtin(__builtin_amdgcn_rcpf)
    return __builtin_amdgcn_rcpf(x);
#else
    return 1.0f / x;
#endif
}
__device__ __forceinline__ float fsig(float x) {
    return frcp(1.0f + fexp2(-1.44269504089f * x));
}
__device__ __forceinline__ float ftanh(float x) {
    float e = fexp2(2.88539008178f * x);
    return 1.0f - 2.0f * frcp(e + 1.0f);
}

// LDS-only barrier: drain lgkm (LDS ops) but NOT vmcnt.
__device__ __forceinline__ void lds_barrier() {
    asm volatile("s_waitcnt lgkmcnt(0)\n\ts_barrier" ::: "memory");
}

// Async global->LDS 16B. lds base must be wave-uniform; HW writes lane l's
// 16B at base + l*16 (measured m104/m108). Size arg must be a literal.
__device__ __forceinline__ void async_load16(const void* g, void* l) {
    __builtin_amdgcn_global_load_lds(
        (const __attribute__((address_space(1))) void*)g,
        (__attribute__((address_space(3))) void*)l, 16, 0, 0);
}

// ---------------------------------------------------------------------------
// P0a: fp32 -> bf16 (n multiple of 4)
__global__ __launch_bounds__(256) void k_f2bf(const float* __restrict__ in,
                                              ushort_t* __restrict__ out, int n) {
    int i = (blockIdx.x * 256 + threadIdx.x) * 4;
    if (i + 3 < n) {
        float4 v = *(const float4*)&in[i];
        ushort4 o;
        o.x = f2bf(v.x); o.y = f2bf(v.y); o.z = f2bf(v.z); o.w = f2bf(v.w);
        *(ushort4*)&out[i] = o;
    }
}

// P0b: Wih fp32 -> bf16 with gate-permuted ROW order:
//   dst[d][(n&255)*4 + (n>>8)][k] = src_d[n][k]
__global__ __launch_bounds__(256) void k_wih(const float* __restrict__ wihf,
                                             const float* __restrict__ wihb,
                                             ushort_t* __restrict__ dst) {
    int d = blockIdx.y;
    int n = blockIdx.x * 4 + (threadIdx.x >> 6);   // 0..1023
    int l = threadIdx.x & 63;
    const float* src = (d ? wihb : wihf) + (size_t)n * 256;
    float4 v = *(const float4*)&src[l * 4];
    int np = (n & 255) * 4 + (n >> 8);
    ushort4 o;
    o.x = f2bf(v.x); o.y = f2bf(v.y); o.z = f2bf(v.z); o.w = f2bf(v.w);
    *(ushort4*)&dst[((size_t)d * 1024 + np) * 256 + l * 4] = o;
}

// P0c: permuted bias vectors bv[d][(n&255)*4 + (n>>8)] = bih_d[n] + bhh_d[n]
__global__ __launch_bounds__(256) void k_bias(const float* __restrict__ bihf,
                                              const float* __restrict__ bhhf,
                                              const float* __restrict__ bihb,
                                              const float* __restrict__ bhhb,
                                              float* __restrict__ bv) {
    int i = blockIdx.x * 256 + threadIdx.x;   // 0..2047
    int d = i >> 10, n = i & 1023;
    float s = d ? (bihb[n] + bhhb[n]) : (bihf[n] + bhhf[n]);
    bv[d * 1024 + (n & 255) * 4 + (n >> 8)] = s;
}

// P0d: quantize Whh rows to int8, packed into mfma_i32_16x16x64_i8
// A-fragment order. Fragment (Mt,Kt): lane l holds row Mt*16+(l&15),
// k = Kt*64 + (l>>4)*16 + {0..15} (4 dwords, byte0 = lowest k).
//   Mt = row_p>>4, rl = row_p&15, Kt = kc>>4, lg = (kc>>2)&3, dw = kc&3
//   wmf[d*65536 + ((Mt*4+Kt)*64 + lg*16 + rl)*4 + dw] = packed
__global__ __launch_bounds__(256) void k_quant(const float* __restrict__ whhf,
                                               const float* __restrict__ whhb,
                                               int* __restrict__ wmf,
                                               float* __restrict__ fscale4) {
    int rowg = blockIdx.x * 4 + (threadIdx.x >> 6);   // 0..2047
    int l = threadIdx.x & 63;                          // = kc
    int d = rowg >> 10;
    int row = rowg & 1023;
    const float* W = (d ? whhb : whhf) + (size_t)row * 256;
    float4 v = *(const float4*)&W[l * 4];
    float m = fmaxf(fmaxf(fabsf(v.x), fabsf(v.y)), fmaxf(fabsf(v.z), fabsf(v.w)));
    #pragma unroll
    for (int off = 32; off > 0; off >>= 1) m = fmaxf(m, __shfl_xor(m, off));
    float inv = (m > 0.0f) ? (127.0f / m) : 0.0f;
    int q0 = __float2int_rn(v.x * inv);
    int q1 = __float2int_rn(v.y * inv);
    int q2 = __float2int_rn(v.z * inv);
    int q3 = __float2int_rn(v.w * inv);
    q0 = min(127, max(-127, q0)); q1 = min(127, max(-127, q1));
    q2 = min(127, max(-127, q2)); q3 = min(127, max(-127, q3));
    int packed = (q0 & 255) | ((q1 & 255) << 8) | ((q2 & 255) << 16) | ((q3 & 255) << 24);
    int j = row & 255, gate = row >> 8;
    int row_p = j * 4 + gate;
    int Mt = row_p >> 4, rl = row_p & 15;
    int Kt = l >> 4, lg = (l >> 2) & 3, dw = l & 3;
    wmf[d * 65536 + ((Mt * 4 + Kt) * 64 + lg * 16 + rl) * 4 + dw] = packed;
    if (l == 0) fscale4[d * 1024 + row_p] = m / (127.0f * 127.0f);
}

// ---------------------------------------------------------------------------
// P1: bf16 GEMM, 2-deep pipelined global_load_lds staging.
// Wave wv stages bytes wv*1024..+1023 of each half-tile (lane l at +l*16);
// the data loaded for LDS chunk cb of row r is source chunk (cb-(r>>1))&3,
// so staged bytes equal the LDSOFF-swizzled layout (reader unchanged).
#define LDSOFF(r, kc) ((r) * 32 + ((((kc) + ((r) >> 1)) & 3) * 8))

__global__ __launch_bounds__(256) void k_gemm(const ushort_t* __restrict__ A,
                                              const ushort_t* __restrict__ Bw,
                                              const float* __restrict__ biasv,
                                              const int* __restrict__ lens,
                                              ushort_t* __restrict__ Xp) {
    const int dir = blockIdx.z;
    const int tn = blockIdx.x;   // 0..7
    const int tm = blockIdx.y;   // 0..255

    // Length-aware tile skip: this tile covers b = tm>>2,
    // t in [(tm&3)*128, +128). k_rec never reads rows t >= len.
    {
        int lenb = lens[tm >> 2];
        if (lenb > 512) lenb = 512;
        if ((tm & 3) * 128 >= lenb) return;   // block-uniform branch
    }

    const ushort_t* Bmat = Bw + dir * 262144;
    const float* bv = biasv + dir * 1024;
    ushort_t* C = Xp + (size_t)dir * 33554432;
    const int tid = threadIdx.x;
    const int w = tid >> 6, l = tid & 63;
    const int wm = w & 1, wn = w >> 1;

    __shared__ ushort_t As[2][4096] __attribute__((aligned(16)));
    __shared__ ushort_t Bs[2][4096] __attribute__((aligned(16)));

    f32x4 acc[4][4];
    #pragma unroll
    for (int i = 0; i < 4; i++)
        #pragma unroll
        for (int jj = 0; jj < 4; jj++) acc[i][jj] = (f32x4){0.f, 0.f, 0.f, 0.f};

    // Staging geometry: thread tid covers rows {r0, r0+64}, LDS col-chunk cb.
    // Source col-chunk cs = (cb - (r0>>1)) & 3 (same for both row halves).
    const int r0 = tid >> 2, cb = tid & 3;
    const int cs = (cb - (r0 >> 1)) & 3;
    const ushort_t* Arow0 = &A[(size_t)(tm * 128 + r0) * 256 + cs * 8];
    const ushort_t* Arow1 = Arow0 + (size_t)64 * 256;
    const ushort_t* Brow0 = &Bmat[(size_t)(tn * 128 + r0) * 256 + cs * 8];
    const ushort_t* Brow1 = Brow0 + (size_t)64 * 256;
    const int lw = w * 512;   // wave-uniform LDS base (ushorts); lane at +l*16B

#define GISSUE(KB, CUR)                                   \
    async_load16(Arow0 + (KB) * 32, &As[CUR][lw]);        \
    async_load16(Arow1 + (KB) * 32, &As[CUR][2048 + lw]); \
    async_load16(Brow0 + (KB) * 32, &Bs[CUR][lw]);        \
    async_load16(Brow1 + (KB) * 32, &Bs[CUR][2048 + lw]);

#define GCOMPUTE(CUR)                                                         \
    {                                                                         \
        short8 af[4], bfr[4];                                                 \
        const int q = l >> 4;                                                 \
        _Pragma("unroll")                                                     \
        for (int mt = 0; mt < 4; mt++) {                                      \
            int rr = wm * 64 + mt * 16 + (l & 15);                            \
            af[mt] = *(const short8*)&As[CUR][LDSOFF(rr, q)];                 \
        }                                                                     \
        _Pragma("unroll")                                                     \
        for (int nt = 0; nt < 4; nt++) {                                      \
            int rr = wn * 64 + nt * 16 + (l & 15);                            \
            bfr[nt] = *(const short8*)&Bs[CUR][LDSOFF(rr, q)];                \
        }                                                                     \
        _Pragma("unroll")                                                     \
        for (int mt = 0; mt < 4; mt++)                                        \
            _Pragma("unroll")                                                 \
            for (int nt = 0; nt < 4; nt++)                                    \
                acc[mt][nt] = __builtin_amdgcn_mfma_f32_16x16x32_bf16(        \
                    af[mt], bfr[nt], acc[mt][nt], 0, 0, 0);                   \
    }

// One pipeline step: wait own oldest loads (counted, not 0) + barrier in a
// single asm (memory clobber: ds_reads can't slip above the barrier), then
// compute, then lgkm-barrier (all reads of CUR done), then refill CUR.
#define GSTEP(KB, CUR, VML, DOISSUE)                                          \
    asm volatile("s_waitcnt vmcnt(" VML ")\n\ts_barrier" ::: "memory");       \
    GCOMPUTE(CUR);                                                            \
    lds_barrier();                                                            \
    if (DOISSUE) { GISSUE((KB) + 2, CUR) }

    GISSUE(0, 0)
    GISSUE(1, 1)
    GSTEP(0, 0, "4", 1)
    GSTEP(1, 1, "4", 1)
    GSTEP(2, 0, "4", 1)
    GSTEP(3, 1, "4", 1)
    GSTEP(4, 0, "4", 1)
    GSTEP(5, 1, "4", 1)
    GSTEP(6, 0, "4", 0)
    GSTEP(7, 1, "0", 0)
#undef GSTEP
#undef GCOMPUTE
#undef GISSUE

    #pragma unroll
    for (int nt = 0; nt < 4; nt++) {
        int n = tn * 128 + wn * 64 + nt * 16 + (l & 15);
        float bn = bv[n];
        #pragma unroll
        for (int mt = 0; mt < 4; mt++) {
            #pragma unroll
            for (int rr = 0; rr < 4; rr++) {
                int m = tm * 128 + wm * 64 + mt * 16 + (l >> 4) * 4 + rr;
                C[(size_t)m * 1024 + n] = f2bf(acc[mt][nt][rr] + bn);
            }
        }
    }
}

// ---------------------------------------------------------------------------
// P2: recurrence. grid (64 batch, 2 dir) x 512 threads (8 waves).
// Wave w owns M-tiles w*8..w*8+7 (units w*32..w*32+31).
// Lane l: rg = l>>4, til = l&7; active lanes ((l&15)<8) each own
// unit j = (w*8+til)*4 + rg and hold its persistent c_state.
__global__ __launch_bounds__(512, 2) void k_rec(const ushort_t* __restrict__ xproj,
                                                const int* __restrict__ wmf,
                                                const float* __restrict__ fscale4,
                                                const int* __restrict__ lens,
                                                float* __restrict__ out) {
    const int b = blockIdx.x, d = blockIdx.y;
    const int tid = threadIdx.x;
    const int w = tid >> 6, l = tid & 63;
    int len = lens[b];
    if (len < 1) len = 1;
    if (len > 512) len = 512;
    const int lenm1 = len - 1;
    const bool dneg = (d != 0);
    const ushort_t* xp = xproj + ((size_t)d * 64 + b) * 524288;  // 512*1024

    const int rg = l >> 4;            // 0..3
    const int rg16 = rg * 16;
    const int til = l & 7;
    const bool act = (l & 15) < 8;
    const int j = (w * 8 + til) * 4 + rg;   // unit 0..255

    // 32 A-fragments (128 dwords) pinned in VGPRs.
    i32x4 wf[8][4];
    const int* wb = wmf + d * 65536;
    #pragma unroll
    for (int i = 0; i < 8; i++)
        #pragma unroll
        for (int kt = 0; kt < 4; kt++)
            wf[i][kt] = *(const i32x4*)&wb[(((w * 8 + i) * 4 + kt) * 64 + l) * 4];
    #pragma unroll
    for (int i = 0; i < 8; i++)
        #pragma unroll
        for (int kt = 0; kt < 4; kt++)
            asm volatile("" : "+v"(wf[i][kt]));

    float4 fr = *(const float4*)&fscale4[d * 1024 + 4 * j];   // loop-invariant

    __shared__ char h8[2][256] __attribute__((aligned(16)));
    if (tid < 64) ((int*)h8)[tid] = 0;   // zero h8[0]

    // zero-fill this direction's half for t in [len, 512)
    {
        float4 z = {0.f, 0.f, 0.f, 0.f};
        int total4 = (512 - len) * 64;
        for (int i = tid; i < total4; i += 512) {
            int t = len + (i >> 6);
            int c4 = i & 63;
            *(float4*)&out[((size_t)b * 512 + t) * 512 + d * 256 + c4 * 4] = z;
        }
    }
    __syncthreads();

    float c_state = 0.0f;
    const i32x4 z4 = {0, 0, 0, 0};
    // lane-fixed byte pointers; per-step offsets are wave-uniform t*2048.
    const char* const xpl = (const char*)(xp + 4 * j);             // x row t: +t*2048
    char* const outl = (char*)(out + (size_t)b * 262144 + d * 256 + j);  // row t: +t*2048

    // x values for steps s and s+1 (loaded 2 steps ahead, no rotation movs).
    uint2 xe = *(const uint2*)(xpl + (size_t)(dneg ? lenm1 : 0) * 2048);
    uint2 xo;
    {
        int sc = (1 < lenm1) ? 1 : lenm1;
        xo = *(const uint2*)(xpl + (size_t)(dneg ? (lenm1 - sc) : sc) * 2048);
    }

    // One recurrence step at compile-time h8 parity (RB -> read, WB -> write).
    // XREG holds x for this step; it is reloaded with step S+2's row.
#define REC_STEP(RB, WB, XREG, S)                                              \
    do {                                                                       \
        const char* hbp = (const char*)h8[RB];                                 \
        i32x4 h0 = *(const i32x4*)(hbp + rg16);                                \
        i32x4 h1 = *(const i32x4*)(hbp + 64 + rg16);                           \
        i32x4 h2 = *(const i32x4*)(hbp + 128 + rg16);                          \
        i32x4 h3 = *(const i32x4*)(hbp + 192 + rg16);                          \
        uint2 xc = XREG;                                                       \
        {                                                                      \
            int sc2 = (S) + 2; if (sc2 > lenm1) sc2 = lenm1;                   \
            int t2 = dneg ? (lenm1 - sc2) : sc2;                               \
            XREG = *(const uint2*)(xpl + (size_t)t2 * 2048);                   \
        }                                                                      \
        i32x4 acc[8];                                                          \
        _Pragma("unroll")                                                      \
        for (int i = 0; i < 8; i++)                                            \
            acc[i] = __builtin_amdgcn_mfma_i32_16x16x64_i8(wf[i][0], h0, z4, 0, 0, 0); \
        _Pragma("unroll")                                                      \
        for (int i = 0; i < 8; i++)                                            \
            acc[i] = __builtin_amdgcn_mfma_i32_16x16x64_i8(wf[i][1], h1, acc[i], 0, 0, 0); \
        _Pragma("unroll")                                                      \
        for (int i = 0; i < 8; i++)                                            \
            acc[i] = __builtin_amdgcn_mfma_i32_16x16x64_i8(wf[i][2], h2, acc[i], 0, 0, 0); \
        _Pragma("unroll")                                                      \
        for (int i = 0; i < 8; i++)                                            \
            acc[i] = __builtin_amdgcn_mfma_i32_16x16x64_i8(wf[i][3], h3, acc[i], 0, 0, 0); \
        if (act) {                                                             \
            i32x4 q0 = (til & 1) ? acc[1] : acc[0];                            \
            i32x4 q1 = (til & 1) ? acc[3] : acc[2];                            \
            i32x4 q2 = (til & 1) ? acc[5] : acc[4];                            \
            i32x4 q3 = (til & 1) ? acc[7] : acc[6];                            \
            i32x4 r0 = (til & 2) ? q1 : q0;                                    \
            i32x4 r1 = (til & 2) ? q3 : q2;                                    \
            i32x4 u  = (til & 4) ? r1 : r0;                                    \
            float pi = bf2f((ushort_t)(xc.x & 0xffffu)) + fr.x * (float)u.x;   \
            float pf = bf2f((ushort_t)(xc.x >> 16))     + fr.y * (float)u.y;   \
            float pg = bf2f((ushort_t)(xc.y & 0xffffu)) + fr.z * (float)u.z;   \
            float po = bf2f((ushort_t)(xc.y >> 16))     + fr.w * (float)u.w;   \
            float ig = fsig(pi), fg = fsig(pf), gg = ftanh(pg), og = fsig(po); \
            c_state = fg * c_state + ig * gg;                                  \
            float h = og * ftanh(c_state);                                     \
            int qq = __float2int_rn(h * 127.0f);                               \
            qq = min(127, max(-127, qq));                                      \
            h8[WB][j] = (char)qq;                                              \
            int t = dneg ? (lenm1 - (S)) : (S);                                \
            *(float*)(outl + (size_t)t * 2048) = h;                            \
        }                                                                      \
        lds_barrier();                                                         \
    } while (0)

    int s = 0;
    for (; s + 1 < len; s += 2) {
        REC_STEP(0, 1, xe, s);
        REC_STEP(1, 0, xo, s + 1);
    }
    if (len & 1) {
        REC_STEP(0, 1, xe, s);
    }
#undef REC_STEP
}

// ---------------------------------------------------------------------------
extern "C" void kernel_launch(void* const* d_in, const int* in_sizes, int n_in,
                              void* d_out, int out_size, void* d_ws, size_t ws_size,
                              hipStream_t stream) {
    (void)in_sizes; (void)n_in; (void)out_size;
    const float* x    = (const float*)d_in[0];
    const int*   lens = (const int*)d_in[1];
    const float* wihf = (const float*)d_in[2];
    const float* whhf = (const float*)d_in[3];
    const float* bihf = (const float*)d_in[4];
    const float* bhhf = (const float*)d_in[5];
    const float* wihb = (const float*)d_in[6];
    const float* whhb = (const float*)d_in[7];
    const float* bihb = (const float*)d_in[8];
    const float* bhhb = (const float*)d_in[9];
    float* out = (float*)d_out;

    char* ws = (char*)d_ws;
    ushort_t* xbf    = (ushort_t*)(ws + 0);          //  16,777,216 B
    ushort_t* wihbf  = (ushort_t*)(ws + 16777216);   //   1,048,576 B
    float*    biasv  = (float*)(ws + 17825792);      //       8,192 B
    int*      wmf    = (int*)(ws + 17833984);        //     524,288 B
    float*    fscale4= (float*)(ws + 18358272);      //       8,192 B
    ushort_t* xproj  = (ushort_t*)(ws + 18366464);   // 134,217,728 B
    const size_t REQ = 18366464 + 134217728ull;
    if (ws_size < REQ) {
        fprintf(stderr, "kernel_launch: ws too small: %zu < %zu\n", ws_size, REQ);
    }

    k_f2bf<<<8192, 256, 0, stream>>>(x, xbf, 8388608);
    k_wih<<<dim3(256, 2), 256, 0, stream>>>(wihf, wihb, wihbf);
    k_bias<<<8, 256, 0, stream>>>(bihf, bhhf, bihb, bhhb, biasv);
    k_quant<<<512, 256, 0, stream>>>(whhf, whhb, wmf, fscale4);
    k_gemm<<<dim3(8, 256, 2), 256, 0, stream>>>(xbf, wihbf, biasv, lens, xproj);
    k_rec<<<dim3(64, 2), 512, 0, stream>>>(xproj, wmf, fscale4, lens, out);
}